// Round 7
// baseline (336.306 us; speedup 1.0000x reference)
//
#include <hip/hip_runtime.h>
#include <math.h>

#define NUM_HEADS 8
#define NUM_GROUPS 32
#define EPS 1e-5f

constexpr int B  = 16;
constexpr int C  = 512;
constexpr int HW = 1024;   // 32*32
constexpr int HD = 64;

typedef short bf16x8 __attribute__((ext_vector_type(8)));
typedef float f32x4  __attribute__((ext_vector_type(4)));

#define QSCALE 0.1803368801111f  /* 0.125 * log2(e): softmax done in exp2 space */

__device__ inline unsigned short f2bf(float f) {
    union { float f; unsigned int u; } v; v.f = f;
    unsigned int r = (v.u + 0x7FFFu + ((v.u >> 16) & 1u)) >> 16;
    return (unsigned short)r;
}

// pack two fp32 -> bf16 pair by truncation, single v_perm_b32
__device__ __forceinline__ unsigned int pack_trunc(float lo, float hi) {
    return __builtin_amdgcn_perm(__float_as_uint(hi), __float_as_uint(lo), 0x07060302u);
}

// async global->LDS, 16B per lane. LDS dest = wave-uniform base + lane*16.
__device__ __forceinline__ void gld_lds16(void* lds, const void* g) {
    __builtin_amdgcn_global_load_lds(
        (const __attribute__((address_space(1))) void*)g,
        (__attribute__((address_space(3))) void*)lds, 16, 0, 0);
}

// ---------------------------------------------------------------------------
// Kernel 1: GroupNorm -> xnT bf16 [b][t=1024][c=512]. Single pass (regs).
// ---------------------------------------------------------------------------
__global__ __launch_bounds__(256)
void groupnorm_t_kernel(const float* __restrict__ x,
                        const float* __restrict__ gamma,
                        const float* __restrict__ beta,
                        unsigned short* __restrict__ xnT) {
    const int bg = blockIdx.x;
    const int b = bg >> 5, g = bg & 31;
    const size_t base = ((size_t)b * C + (size_t)g * 16) * HW;

    float v[4][16];
    float sum = 0.f, sumsq = 0.f;
    #pragma unroll
    for (int p = 0; p < 4; ++p) {
        const int t = threadIdx.x + p * 256;
        #pragma unroll
        for (int cl = 0; cl < 16; ++cl) {
            const float f = x[base + (size_t)cl * HW + t];
            v[p][cl] = f;
            sum += f;
            sumsq += f * f;
        }
    }
    #pragma unroll
    for (int off = 32; off > 0; off >>= 1) {
        sum   += __shfl_down(sum, off, 64);
        sumsq += __shfl_down(sumsq, off, 64);
    }
    __shared__ float s_sum[4], s_sq[4];
    const int wid = threadIdx.x >> 6, lane = threadIdx.x & 63;
    if (lane == 0) { s_sum[wid] = sum; s_sq[wid] = sumsq; }
    __syncthreads();
    const float tsum = s_sum[0] + s_sum[1] + s_sum[2] + s_sum[3];
    const float tsq  = s_sq[0] + s_sq[1] + s_sq[2] + s_sq[3];
    const float mean = tsum * (1.0f / 16384.f);
    const float var  = tsq * (1.0f / 16384.f) - mean * mean;
    const float rstd = rsqrtf(var + EPS);

    float ga[16], be[16];
    #pragma unroll
    for (int cl = 0; cl < 16; ++cl) {
        ga[cl] = gamma[g * 16 + cl] * rstd;
        be[cl] = beta[g * 16 + cl] - mean * ga[cl];
    }

    #pragma unroll
    for (int p = 0; p < 4; ++p) {
        const int t = threadIdx.x + p * 256;
        unsigned short pk[16];
        #pragma unroll
        for (int cl = 0; cl < 16; ++cl)
            pk[cl] = f2bf(v[p][cl] * ga[cl] + be[cl]);
        unsigned short* dst = xnT + ((size_t)(b * 1024 + t)) * 512 + g * 16;
        *(uint4*)dst = *(const uint4*)pk;
        *(uint4*)(dst + 8) = *(const uint4*)(pk + 8);
    }
}

// ---------------------------------------------------------------------------
// Kernel 2: weight conversion fp32 -> bf16.
// ---------------------------------------------------------------------------
__global__ __launch_bounds__(256)
void wconv_kernel(const float* __restrict__ qkv_w,
                  const float* __restrict__ proj_w,
                  unsigned short* __restrict__ wqb) {
    const int i = blockIdx.x * 256 + threadIdx.x;   // float4 index
    const int n1 = 786432 / 4;
    const int nt = 1048576 / 4;
    if (i >= nt) return;
    const float4 v = (i < n1) ? ((const float4*)qkv_w)[i]
                              : ((const float4*)proj_w)[i - n1];
    ushort4 r;
    r.x = f2bf(v.x); r.y = f2bf(v.y); r.z = f2bf(v.z); r.w = f2bf(v.w);
    ((ushort4*)wqb)[i] = r;
}

// ---------------------------------------------------------------------------
// Shared MFMA GEMM core (unchanged).
// ---------------------------------------------------------------------------
__device__ __forceinline__ void mfma_gemm_core(const char* __restrict__ Ab,
                                               const char* __restrict__ Bb,
                                               unsigned short* As,
                                               unsigned short* Bs,
                                               f32x4 acc[4][4]) {
    const int tid = threadIdx.x;
    const int w = tid >> 6, lane = tid & 63;
    const int lo = lane & 15, q4 = lane >> 4;
    const int wm = w >> 1, wn = w & 1;
    const int lrow = lane >> 2, lkc = lane & 3;

    for (int k0 = 0; k0 < 512; k0 += 32) {
        __syncthreads();
        #pragma unroll
        for (int i = 0; i < 2; ++i) {
            const int row = w * 32 + i * 16 + lrow;
            const int kc = lkc ^ ((row >> 1) & 3);   // swizzle k-chunk
            const size_t goff = (size_t)row * 1024 + k0 * 2 + kc * 16;
            gld_lds16((char*)As + w * 2048 + i * 1024, Ab + goff);
            gld_lds16((char*)Bs + w * 2048 + i * 1024, Bb + goff);
        }
        __syncthreads();

        bf16x8 af[4], bfr[4];
        #pragma unroll
        for (int i = 0; i < 4; ++i) {
            const int ra = wm * 64 + i * 16 + lo;
            af[i]  = *(const bf16x8*)(As + ra * 32 + (q4 ^ ((ra >> 1) & 3)) * 8);
            const int rb = wn * 64 + i * 16 + lo;
            bfr[i] = *(const bf16x8*)(Bs + rb * 32 + (q4 ^ ((rb >> 1) & 3)) * 8);
        }
        #pragma unroll
        for (int mi = 0; mi < 4; ++mi)
            #pragma unroll
            for (int ni = 0; ni < 4; ++ni)
                acc[mi][ni] = __builtin_amdgcn_mfma_f32_16x16x32_bf16(
                    af[mi], bfr[ni], acc[mi][ni], 0, 0, 0);
    }
}

// ---------------------------------------------------------------------------
// Kernel 3: QKV projection GEMM (unchanged from round 6).
// ---------------------------------------------------------------------------
__global__ __launch_bounds__(256)
void qkv_mfma_kernel(const unsigned short* __restrict__ wqb,
                     const unsigned short* __restrict__ xnT,
                     const float* __restrict__ qkv_b,
                     unsigned short* __restrict__ Qt,
                     unsigned short* __restrict__ Kt,
                     unsigned short* __restrict__ Vb) {
    __shared__ __align__(16) unsigned short SMEM[8192];  // As | Bs, reused by V epilogue
    unsigned short* As = SMEM;
    unsigned short* Bs = SMEM + 4096;
    const int batch = blockIdx.z;
    const int mBase = blockIdx.y * 128, nBase = blockIdx.x * 128;

    f32x4 acc[4][4] = {};
    mfma_gemm_core((const char*)(wqb + (size_t)mBase * 512),
                   (const char*)(xnT + ((size_t)batch * 1024 + nBase) * 512),
                   As, Bs, acc);

    const int tid = threadIdx.x;
    const int w = tid >> 6, lane = tid & 63;
    const int lo = lane & 15, q4 = lane >> 4;
    const int wm = w >> 1, wn = w & 1;
    const int mw = mBase + wm * 64;          // head-aligned 64-row chunk
    const int tb = nBase + wn * 64;

    __syncthreads();   // all waves done with GEMM LDS

    if (mw < 1024) {
        const bool isQ = mw < 512;
        const int head = (mw >> 6) & 7;
        unsigned short* dst = (isQ ? Qt : Kt) + (((size_t)batch * 8 + head) << 16);
        const float sc = isQ ? QSCALE : 1.0f;
        #pragma unroll
        for (int mi = 0; mi < 4; ++mi) {
            const float4 bq = *(const float4*)(qkv_b + mw + mi * 16 + q4 * 4);
            #pragma unroll
            for (int ni = 0; ni < 4; ++ni) {
                const int t = tb + ni * 16 + lo;
                ushort4 pk;
                pk.x = f2bf((acc[mi][ni][0] + bq.x) * sc);
                pk.y = f2bf((acc[mi][ni][1] + bq.y) * sc);
                pk.z = f2bf((acc[mi][ni][2] + bq.z) * sc);
                pk.w = f2bf((acc[mi][ni][3] + bq.w) * sc);
                *(ushort4*)(dst + (size_t)t * 64 + mi * 16 + q4 * 4) = pk;
            }
        }
    } else {
        // V: LDS transpose -> coalesced uint4 stores into Vb[b][d][t].
        unsigned short* T = SMEM + w * 2048;         // 32 x 64 shorts
        unsigned short* Vrow = Vb + (size_t)batch * 524288 + (size_t)(mw - 1024) * 1024 + tb;
        const int rl8 = lane >> 3, c8 = lane & 7;
        #pragma unroll
        for (int p = 0; p < 2; ++p) {
            #pragma unroll
            for (int mi2 = 0; mi2 < 2; ++mi2) {
                const int mi = 2 * p + mi2;
                const float4 bq = *(const float4*)(qkv_b + mw + mi * 16 + q4 * 4);
                const int dl = mi2 * 16 + q4 * 4;
                #pragma unroll
                for (int ni = 0; ni < 4; ++ni) {
                    const int tl = ni * 16 + lo;
                    T[(dl + 0) * 64 + tl] = f2bf(acc[mi][ni][0] + bq.x);
                    T[(dl + 1) * 64 + tl] = f2bf(acc[mi][ni][1] + bq.y);
                    T[(dl + 2) * 64 + tl] = f2bf(acc[mi][ni][2] + bq.z);
                    T[(dl + 3) * 64 + tl] = f2bf(acc[mi][ni][3] + bq.w);
                }
            }
            #pragma unroll
            for (int i = 0; i < 4; ++i) {
                const int dl = i * 8 + rl8;
                const uint4 val = *(const uint4*)&T[dl * 64 + c8 * 8];
                *(uint4*)(Vrow + (size_t)(p * 32 + dl) * 1024 + c8 * 8) = val;
            }
        }
    }
}

// ---------------------------------------------------------------------------
// Kernel 4: MFMA flash attention, s-split. Block = (bh, t-tile 256, s-half 512).
// 8 chunks. Single-buffer K/V staging; per-wave Ps; two mt-pair phases to cap
// register pressure. Unnormalized exp2 softmax; bf16 partial O + fp32 l out.
// XCD-swizzled 1D grid: all 8 blocks of one bh share id%8.
// ---------------------------------------------------------------------------
__global__ __launch_bounds__(256, 3)
void attn_mfma_kernel(const unsigned short* __restrict__ Qt,
                      const unsigned short* __restrict__ Kt,
                      const unsigned short* __restrict__ Vb,
                      unsigned short* __restrict__ Opart,
                      float* __restrict__ lpart) {
    const int blk = blockIdx.x;
    const int cxd = blk & 7, j = blk >> 3;
    const int bh = cxd * 16 + (j >> 3);
    const int ts = j & 7;
    const int tt = ts >> 1, sh = ts & 1;
    const int b = bh >> 3, h = bh & 7;
    const int tBase = tt * 256;
    const int sBase = sh * 512;
    const int tid = threadIdx.x;
    const int w = tid >> 6, lane = tid & 63;
    const int lo = lane & 15, q4 = lane >> 4;
    const int xr = lo & 7;

    __shared__ __align__(16) unsigned short Ks[64 * 64];      // [s][d] swizzled
    __shared__ __align__(16) unsigned short Vs[64 * 64];      // [d][s] swizzled
    __shared__ __align__(16) unsigned short Ps[4 * 4096];     // per-wave [t][s] swizzled

    const unsigned short* Kp = Kt + ((size_t)bh << 16);
    const unsigned short* Vp = Vb + ((size_t)b * 512 + h * 64) * 1024;

    // persistent Q B-frags
    bf16x8 qf[4][2];
    {
        const unsigned short* Qp = Qt + ((size_t)bh * 1024 + tBase + 64 * w) * 64;
        #pragma unroll
        for (int nt = 0; nt < 4; ++nt) {
            qf[nt][0] = *(const bf16x8*)(Qp + (size_t)(16 * nt + lo) * 64 + 8 * q4);
            qf[nt][1] = *(const bf16x8*)(Qp + (size_t)(16 * nt + lo) * 64 + 32 + 8 * q4);
        }
    }

    const int rl = lane >> 3, p8 = lane & 7;
    auto stage = [&](int s0) {
        #pragma unroll
        for (int cc = 0; cc < 2; ++cc) {
            const int r = 16 * w + 8 * cc + rl;
            const int jj = p8 ^ (r & 7);
            gld_lds16(Ks + (16 * w + 8 * cc) * 64, Kp + (size_t)(s0 + r) * 64 + jj * 8);
            gld_lds16(Vs + (16 * w + 8 * cc) * 64, Vp + (size_t)r * 1024 + s0 + jj * 8);
        }
    };

    f32x4 oacc[4][4] = {};
    float lrun[4] = {0.f, 0.f, 0.f, 0.f};
    unsigned short* Pw = Ps + w * 4096;

    for (int i = 0; i < 8; ++i) {
        if (i) __syncthreads();       // all waves done reading Ks/Vs of chunk i-1
        stage(sBase + i * 64);
        __syncthreads();              // vmcnt drain + visibility
        #pragma unroll
        for (int ph = 0; ph < 2; ++ph) {
            // ---- S for mt = 2ph, 2ph+1 ----
            f32x4 sacc[2][4] = {};
            #pragma unroll
            for (int ml = 0; ml < 2; ++ml) {
                const unsigned short* kr = Ks + (16 * (2 * ph + ml) + lo) * 64;
                const bf16x8 a0 = *(const bf16x8*)(kr + ((q4    ) ^ xr) * 8);
                const bf16x8 a1 = *(const bf16x8*)(kr + ((q4 + 4) ^ xr) * 8);
                #pragma unroll
                for (int nt = 0; nt < 4; ++nt) {
                    sacc[ml][nt] = __builtin_amdgcn_mfma_f32_16x16x32_bf16(a0, qf[nt][0], sacc[ml][nt], 0, 0, 0);
                    sacc[ml][nt] = __builtin_amdgcn_mfma_f32_16x16x32_bf16(a1, qf[nt][1], sacc[ml][nt], 0, 0, 0);
                }
            }
            // ---- P = exp2(S), accumulate l, pack to LDS ----
            #pragma unroll
            for (int nt = 0; nt < 4; ++nt) {
                const int t = 16 * nt + lo;
                float ps = 0.f;
                #pragma unroll
                for (int ml = 0; ml < 2; ++ml) {
                    const f32x4 s = sacc[ml][nt];
                    const float p0 = exp2f(s[0]);
                    const float p1 = exp2f(s[1]);
                    const float p2 = exp2f(s[2]);
                    const float p3 = exp2f(s[3]);
                    ps += (p0 + p1) + (p2 + p3);
                    uint2 pk;
                    pk.x = pack_trunc(p0, p1);
                    pk.y = pack_trunc(p2, p3);
                    const int sc = 4 * ph + 2 * ml + (q4 >> 1);
                    *(uint2*)(Pw + t * 64 + ((sc ^ xr) * 8) + 4 * (q4 & 1)) = pk;
                }
                lrun[nt] += ps;
            }
            // ---- O^T += V P^T for this s-half (same-wave LDS RAW) ----
            bf16x8 bp[4];
            #pragma unroll
            for (int nt = 0; nt < 4; ++nt)
                bp[nt] = *(const bf16x8*)(Pw + (16 * nt + lo) * 64 + (((q4 + 4 * ph) ^ xr) * 8));
            #pragma unroll
            for (int md = 0; md < 4; ++md) {
                const bf16x8 av = *(const bf16x8*)(Vs + (16 * md + lo) * 64 + (((q4 + 4 * ph) ^ xr) * 8));
                #pragma unroll
                for (int nt = 0; nt < 4; ++nt)
                    oacc[md][nt] = __builtin_amdgcn_mfma_f32_16x16x32_bf16(av, bp[nt], oacc[md][nt], 0, 0, 0);
            }
        }
    }

    // ---- epilogue: partial l (fp32) + partial O (bf16, unnormalized) ----
    const size_t tw = (size_t)tBase + 64 * w;
    const size_t pbase = ((size_t)sh * 128 + bh) * 1024;
    #pragma unroll
    for (int nt = 0; nt < 4; ++nt) {
        float lt = lrun[nt];
        lt += __shfl_xor(lt, 16, 64);
        lt += __shfl_xor(lt, 32, 64);
        const int tl = 16 * nt + lo;
        if (q4 == 0) lpart[pbase + tw + tl] = lt;
        unsigned short* op = Opart + (pbase + tw + tl) * 64;
        #pragma unroll
        for (int md = 0; md < 4; ++md) {
            uint2 pk;
            pk.x = pack_trunc(oacc[md][nt][0], oacc[md][nt][1]);
            pk.y = pack_trunc(oacc[md][nt][2], oacc[md][nt][3]);
            *(uint2*)(op + 16 * md + 4 * q4) = pk;
        }
    }
}

// ---------------------------------------------------------------------------
// Kernel 4b: combine s-half partials -> attnT bf16 [b][t][c].
// ---------------------------------------------------------------------------
__global__ __launch_bounds__(256)
void attn_combine_kernel(const unsigned short* __restrict__ Opart,
                         const float* __restrict__ lpart,
                         unsigned short* __restrict__ attnT) {
    const int idx = blockIdx.x * 256 + threadIdx.x;   // 0 .. 2^20
    const int d8 = idx & 7;
    const int t  = (idx >> 3) & 1023;
    const int bh = idx >> 13;
    const int b = bh >> 3, h = bh & 7;
    const size_t po = ((size_t)bh * 1024 + t) * 64 + d8 * 8;
    const uint4 o0 = *(const uint4*)(Opart + po);
    const uint4 o1 = *(const uint4*)(Opart + ((size_t)128 * 1024 * 64) + po);
    const float l0 = lpart[(size_t)bh * 1024 + t];
    const float l1 = lpart[(size_t)128 * 1024 + (size_t)bh * 1024 + t];
    const float inv = 1.0f / (l0 + l1);
    const unsigned int* a = (const unsigned int*)&o0;
    const unsigned int* c = (const unsigned int*)&o1;
    unsigned int outv[4];
    #pragma unroll
    for (int k = 0; k < 4; ++k) {
        const float alo = __uint_as_float(a[k] << 16);
        const float ahi = __uint_as_float(a[k] & 0xFFFF0000u);
        const float blo = __uint_as_float(c[k] << 16);
        const float bhi = __uint_as_float(c[k] & 0xFFFF0000u);
        outv[k] = pack_trunc((alo + blo) * inv, (ahi + bhi) * inv);
    }
    *(uint4*)(attnT + ((size_t)(b * 1024 + t)) * 512 + h * 64 + d8 * 8) = *(uint4*)outv;
}

// ---------------------------------------------------------------------------
// Kernel 5: proj GEMM + bias + residual, fp32 out (unchanged).
// ---------------------------------------------------------------------------
__global__ __launch_bounds__(256)
void proj_mfma_kernel(const unsigned short* __restrict__ wpb,
                      const unsigned short* __restrict__ attnT,
                      const float* __restrict__ proj_b,
                      const float* __restrict__ x,
                      float* __restrict__ out) {
    __shared__ __align__(16) unsigned short As[128 * 32];
    __shared__ __align__(16) unsigned short Bs[128 * 32];
    const int batch = blockIdx.z;
    const int mBase = blockIdx.y * 128, nBase = blockIdx.x * 128;

    f32x4 acc[4][4] = {};
    mfma_gemm_core((const char*)(wpb + (size_t)mBase * 512),
                   (const char*)(attnT + ((size_t)batch * 1024 + nBase) * 512),
                   As, Bs, acc);

    const int tid = threadIdx.x;
    const int w = tid >> 6, lane = tid & 63;
    const int lo = lane & 15, q4 = lane >> 4;
    const int wm = w >> 1, wn = w & 1;
    const float* xb = x + (size_t)batch * 524288;
    float* ob = out + (size_t)batch * 524288;

    #pragma unroll
    for (int mi = 0; mi < 4; ++mi) {
        const int m0 = mBase + wm * 64 + mi * 16 + q4 * 4;
        const float4 bq = *(const float4*)(proj_b + m0);
        #pragma unroll
        for (int ni = 0; ni < 4; ++ni) {
            const int t = nBase + wn * 64 + ni * 16 + lo;
            const size_t o0 = (size_t)m0 * 1024 + t;
            ob[o0]          = acc[mi][ni][0] + bq.x + xb[o0];
            ob[o0 + 1024]   = acc[mi][ni][1] + bq.y + xb[o0 + 1024];
            ob[o0 + 2048]   = acc[mi][ni][2] + bq.z + xb[o0 + 2048];
            ob[o0 + 3072]   = acc[mi][ni][3] + bq.w + xb[o0 + 3072];
        }
    }
}

// ---------------------------------------------------------------------------
// Launch
// ---------------------------------------------------------------------------
extern "C" void kernel_launch(void* const* d_in, const int* in_sizes, int n_in,
                              void* d_out, int out_size, void* d_ws, size_t ws_size,
                              hipStream_t stream) {
    const float* x        = (const float*)d_in[0];
    const float* gn_gamma = (const float*)d_in[1];
    const float* gn_beta  = (const float*)d_in[2];
    const float* qkv_w    = (const float*)d_in[3];
    const float* qkv_b    = (const float*)d_in[4];
    const float* proj_w   = (const float*)d_in[5];
    const float* proj_b   = (const float*)d_in[6];
    float* out = (float*)d_out;

    // workspace layout (~117 MiB)
    char* wsc = (char*)d_ws;
    unsigned short* xnT   = (unsigned short*)(wsc);              // 16 MiB [b][t][c]
    unsigned short* Qt    = (unsigned short*)(wsc + 16777216);   // 16 MiB [bh][t][d]
    unsigned short* Kt    = (unsigned short*)(wsc + 33554432);   // 16 MiB [bh][t][d]
    unsigned short* Vb    = (unsigned short*)(wsc + 50331648);   // 16 MiB [b][d'][t]
    unsigned short* attnT = (unsigned short*)(wsc + 67108864);   // 16 MiB [b][t][c]
    unsigned short* wqb   = (unsigned short*)(wsc + 83886080);   // 1.5 MiB (wpb follows)
    unsigned short* wpb   = wqb + 786432;                        // 0.5 MiB
    unsigned short* Opart = (unsigned short*)(wsc + 88080384);   // 32 MiB [2][bh][t][d]
    float*          lpart = (float*)(wsc + 121634816);           // 1 MiB  [2][bh][t]

    // 1. GroupNorm -> xnT bf16
    groupnorm_t_kernel<<<B * NUM_GROUPS, 256, 0, stream>>>(x, gn_gamma, gn_beta, xnT);

    // 2. Weights -> bf16
    wconv_kernel<<<1024, 256, 0, stream>>>(qkv_w, proj_w, wqb);

    // 3. QKV MFMA GEMM (writes Qt, Kt, Vb directly)
    {
        dim3 grid(HW / 128, (3 * C) / 128, B);
        qkv_mfma_kernel<<<grid, 256, 0, stream>>>(wqb, xnT, qkv_b, Qt, Kt, Vb);
    }

    // 4. MFMA flash attention, s-split (1024 blocks) -> partials
    attn_mfma_kernel<<<1024, 256, 0, stream>>>(Qt, Kt, Vb, Opart, lpart);

    // 4b. Combine partials -> attnT bf16
    attn_combine_kernel<<<4096, 256, 0, stream>>>(Opart, lpart, attnT);

    // 5. Proj MFMA GEMM + bias + residual -> fp32 out
    {
        dim3 grid(HW / 128, C / 128, B);
        proj_mfma_kernel<<<grid, 256, 0, stream>>>(wpb, attnT, proj_b, x, out);
    }
}

// Round 8
// 222.180 us; speedup vs baseline: 1.5137x; 1.5137x over previous
//
#include <hip/hip_runtime.h>
#include <math.h>

#define NUM_HEADS 8
#define NUM_GROUPS 32
#define EPS 1e-5f

constexpr int B  = 16;
constexpr int C  = 512;
constexpr int HW = 1024;   // 32*32
constexpr int HD = 64;

typedef short bf16x8 __attribute__((ext_vector_type(8)));
typedef float f32x4  __attribute__((ext_vector_type(4)));

#define QSCALE 0.1803368801111f  /* 0.125 * log2(e): softmax done in exp2 space */

__device__ inline unsigned short f2bf(float f) {
    union { float f; unsigned int u; } v; v.f = f;
    unsigned int r = (v.u + 0x7FFFu + ((v.u >> 16) & 1u)) >> 16;
    return (unsigned short)r;
}

// pack two fp32 -> bf16 pair by truncation, single v_perm_b32
__device__ __forceinline__ unsigned int pack_trunc(float lo, float hi) {
    return __builtin_amdgcn_perm(__float_as_uint(hi), __float_as_uint(lo), 0x07060302u);
}

// async global->LDS, 16B per lane. LDS dest = wave-uniform base + lane*16.
__device__ __forceinline__ void gld_lds16(void* lds, const void* g) {
    __builtin_amdgcn_global_load_lds(
        (const __attribute__((address_space(1))) void*)g,
        (__attribute__((address_space(3))) void*)lds, 16, 0, 0);
}

// ---------------------------------------------------------------------------
// Kernel 1: GroupNorm -> xnT bf16 [b][t=1024][c=512]. Single pass (regs).
// ---------------------------------------------------------------------------
__global__ __launch_bounds__(256)
void groupnorm_t_kernel(const float* __restrict__ x,
                        const float* __restrict__ gamma,
                        const float* __restrict__ beta,
                        unsigned short* __restrict__ xnT) {
    const int bg = blockIdx.x;
    const int b = bg >> 5, g = bg & 31;
    const size_t base = ((size_t)b * C + (size_t)g * 16) * HW;

    float v[4][16];
    float sum = 0.f, sumsq = 0.f;
    #pragma unroll
    for (int p = 0; p < 4; ++p) {
        const int t = threadIdx.x + p * 256;
        #pragma unroll
        for (int cl = 0; cl < 16; ++cl) {
            const float f = x[base + (size_t)cl * HW + t];
            v[p][cl] = f;
            sum += f;
            sumsq += f * f;
        }
    }
    #pragma unroll
    for (int off = 32; off > 0; off >>= 1) {
        sum   += __shfl_down(sum, off, 64);
        sumsq += __shfl_down(sumsq, off, 64);
    }
    __shared__ float s_sum[4], s_sq[4];
    const int wid = threadIdx.x >> 6, lane = threadIdx.x & 63;
    if (lane == 0) { s_sum[wid] = sum; s_sq[wid] = sumsq; }
    __syncthreads();
    const float tsum = s_sum[0] + s_sum[1] + s_sum[2] + s_sum[3];
    const float tsq  = s_sq[0] + s_sq[1] + s_sq[2] + s_sq[3];
    const float mean = tsum * (1.0f / 16384.f);
    const float var  = tsq * (1.0f / 16384.f) - mean * mean;
    const float rstd = rsqrtf(var + EPS);

    float ga[16], be[16];
    #pragma unroll
    for (int cl = 0; cl < 16; ++cl) {
        ga[cl] = gamma[g * 16 + cl] * rstd;
        be[cl] = beta[g * 16 + cl] - mean * ga[cl];
    }

    #pragma unroll
    for (int p = 0; p < 4; ++p) {
        const int t = threadIdx.x + p * 256;
        unsigned short pk[16];
        #pragma unroll
        for (int cl = 0; cl < 16; ++cl)
            pk[cl] = f2bf(v[p][cl] * ga[cl] + be[cl]);
        unsigned short* dst = xnT + ((size_t)(b * 1024 + t)) * 512 + g * 16;
        *(uint4*)dst = *(const uint4*)pk;
        *(uint4*)(dst + 8) = *(const uint4*)(pk + 8);
    }
}

// ---------------------------------------------------------------------------
// Kernel 2: weight conversion fp32 -> bf16.
// ---------------------------------------------------------------------------
__global__ __launch_bounds__(256)
void wconv_kernel(const float* __restrict__ qkv_w,
                  const float* __restrict__ proj_w,
                  unsigned short* __restrict__ wqb) {
    const int i = blockIdx.x * 256 + threadIdx.x;   // float4 index
    const int n1 = 786432 / 4;
    const int nt = 1048576 / 4;
    if (i >= nt) return;
    const float4 v = (i < n1) ? ((const float4*)qkv_w)[i]
                              : ((const float4*)proj_w)[i - n1];
    ushort4 r;
    r.x = f2bf(v.x); r.y = f2bf(v.y); r.z = f2bf(v.z); r.w = f2bf(v.w);
    ((ushort4*)wqb)[i] = r;
}

// ---------------------------------------------------------------------------
// Shared MFMA GEMM core (unchanged).
// ---------------------------------------------------------------------------
__device__ __forceinline__ void mfma_gemm_core(const char* __restrict__ Ab,
                                               const char* __restrict__ Bb,
                                               unsigned short* As,
                                               unsigned short* Bs,
                                               f32x4 acc[4][4]) {
    const int tid = threadIdx.x;
    const int w = tid >> 6, lane = tid & 63;
    const int lo = lane & 15, q4 = lane >> 4;
    const int wm = w >> 1, wn = w & 1;
    const int lrow = lane >> 2, lkc = lane & 3;

    for (int k0 = 0; k0 < 512; k0 += 32) {
        __syncthreads();
        #pragma unroll
        for (int i = 0; i < 2; ++i) {
            const int row = w * 32 + i * 16 + lrow;
            const int kc = lkc ^ ((row >> 1) & 3);   // swizzle k-chunk
            const size_t goff = (size_t)row * 1024 + k0 * 2 + kc * 16;
            gld_lds16((char*)As + w * 2048 + i * 1024, Ab + goff);
            gld_lds16((char*)Bs + w * 2048 + i * 1024, Bb + goff);
        }
        __syncthreads();

        bf16x8 af[4], bfr[4];
        #pragma unroll
        for (int i = 0; i < 4; ++i) {
            const int ra = wm * 64 + i * 16 + lo;
            af[i]  = *(const bf16x8*)(As + ra * 32 + (q4 ^ ((ra >> 1) & 3)) * 8);
            const int rb = wn * 64 + i * 16 + lo;
            bfr[i] = *(const bf16x8*)(Bs + rb * 32 + (q4 ^ ((rb >> 1) & 3)) * 8);
        }
        #pragma unroll
        for (int mi = 0; mi < 4; ++mi)
            #pragma unroll
            for (int ni = 0; ni < 4; ++ni)
                acc[mi][ni] = __builtin_amdgcn_mfma_f32_16x16x32_bf16(
                    af[mi], bfr[ni], acc[mi][ni], 0, 0, 0);
    }
}

// ---------------------------------------------------------------------------
// Kernel 3: QKV projection GEMM (unchanged from round 6).
// ---------------------------------------------------------------------------
__global__ __launch_bounds__(256)
void qkv_mfma_kernel(const unsigned short* __restrict__ wqb,
                     const unsigned short* __restrict__ xnT,
                     const float* __restrict__ qkv_b,
                     unsigned short* __restrict__ Qt,
                     unsigned short* __restrict__ Kt,
                     unsigned short* __restrict__ Vb) {
    __shared__ __align__(16) unsigned short SMEM[8192];  // As | Bs, reused by V epilogue
    unsigned short* As = SMEM;
    unsigned short* Bs = SMEM + 4096;
    const int batch = blockIdx.z;
    const int mBase = blockIdx.y * 128, nBase = blockIdx.x * 128;

    f32x4 acc[4][4] = {};
    mfma_gemm_core((const char*)(wqb + (size_t)mBase * 512),
                   (const char*)(xnT + ((size_t)batch * 1024 + nBase) * 512),
                   As, Bs, acc);

    const int tid = threadIdx.x;
    const int w = tid >> 6, lane = tid & 63;
    const int lo = lane & 15, q4 = lane >> 4;
    const int wm = w >> 1, wn = w & 1;
    const int mw = mBase + wm * 64;          // head-aligned 64-row chunk
    const int tb = nBase + wn * 64;

    __syncthreads();   // all waves done with GEMM LDS

    if (mw < 1024) {
        const bool isQ = mw < 512;
        const int head = (mw >> 6) & 7;
        unsigned short* dst = (isQ ? Qt : Kt) + (((size_t)batch * 8 + head) << 16);
        const float sc = isQ ? QSCALE : 1.0f;
        #pragma unroll
        for (int mi = 0; mi < 4; ++mi) {
            const float4 bq = *(const float4*)(qkv_b + mw + mi * 16 + q4 * 4);
            #pragma unroll
            for (int ni = 0; ni < 4; ++ni) {
                const int t = tb + ni * 16 + lo;
                ushort4 pk;
                pk.x = f2bf((acc[mi][ni][0] + bq.x) * sc);
                pk.y = f2bf((acc[mi][ni][1] + bq.y) * sc);
                pk.z = f2bf((acc[mi][ni][2] + bq.z) * sc);
                pk.w = f2bf((acc[mi][ni][3] + bq.w) * sc);
                *(ushort4*)(dst + (size_t)t * 64 + mi * 16 + q4 * 4) = pk;
            }
        }
    } else {
        // V: LDS transpose -> coalesced uint4 stores into Vb[b][d][t].
        unsigned short* T = SMEM + w * 2048;         // 32 x 64 shorts
        unsigned short* Vrow = Vb + (size_t)batch * 524288 + (size_t)(mw - 1024) * 1024 + tb;
        const int rl8 = lane >> 3, c8 = lane & 7;
        #pragma unroll
        for (int p = 0; p < 2; ++p) {
            #pragma unroll
            for (int mi2 = 0; mi2 < 2; ++mi2) {
                const int mi = 2 * p + mi2;
                const float4 bq = *(const float4*)(qkv_b + mw + mi * 16 + q4 * 4);
                const int dl = mi2 * 16 + q4 * 4;
                #pragma unroll
                for (int ni = 0; ni < 4; ++ni) {
                    const int tl = ni * 16 + lo;
                    T[(dl + 0) * 64 + tl] = f2bf(acc[mi][ni][0] + bq.x);
                    T[(dl + 1) * 64 + tl] = f2bf(acc[mi][ni][1] + bq.y);
                    T[(dl + 2) * 64 + tl] = f2bf(acc[mi][ni][2] + bq.z);
                    T[(dl + 3) * 64 + tl] = f2bf(acc[mi][ni][3] + bq.w);
                }
            }
            #pragma unroll
            for (int i = 0; i < 4; ++i) {
                const int dl = i * 8 + rl8;
                const uint4 val = *(const uint4*)&T[dl * 64 + c8 * 8];
                *(uint4*)(Vrow + (size_t)(p * 32 + dl) * 1024 + c8 * 8) = val;
            }
        }
    }
}

// ---------------------------------------------------------------------------
// Kernel 4: MFMA flash attention, t-split: 128 queries/block, 4 waves x 32t,
// full s-loop (16 chunks), single-buffered K/V (32 KB LDS total) -> 4 blk/CU.
// Grid (x=bh, y=tq) x-fastest: the 8 blocks of one bh share id%8 (co-XCD
// K/V L2 reuse — round-6-proven layout). Unnormalized exp2 softmax.
// ---------------------------------------------------------------------------
__global__ __launch_bounds__(256, 4)
void attn_mfma_kernel(const unsigned short* __restrict__ Qt,
                      const unsigned short* __restrict__ Kt,
                      const unsigned short* __restrict__ Vb,
                      unsigned short* __restrict__ attnT) {
    const int bh = blockIdx.x;
    const int b = bh >> 3, h = bh & 7;
    const int tBase = blockIdx.y * 128;
    const int tid = threadIdx.x;
    const int w = tid >> 6, lane = tid & 63;
    const int lo = lane & 15, q4 = lane >> 4;
    const int xr = lo & 7;

    __shared__ __align__(16) unsigned short Ks[64 * 64];    // [s][d] swizzled, 8 KB
    __shared__ __align__(16) unsigned short Vs[64 * 64];    // [d][s] swizzled, 8 KB
    __shared__ __align__(16) unsigned short Ps[4 * 2048];   // per-wave 32t x 64s, 16 KB

    const unsigned short* Kp = Kt + ((size_t)bh << 16);
    const unsigned short* Vp = Vb + ((size_t)b * 512 + h * 64) * 1024;

    // persistent Q B-frags: wave w owns t in [tBase+32w, +32), nt in {0,1}
    bf16x8 qf[2][2];
    {
        const unsigned short* Qp = Qt + ((size_t)bh * 1024 + tBase + 32 * w) * 64;
        #pragma unroll
        for (int nt = 0; nt < 2; ++nt) {
            qf[nt][0] = *(const bf16x8*)(Qp + (size_t)(16 * nt + lo) * 64 + 8 * q4);
            qf[nt][1] = *(const bf16x8*)(Qp + (size_t)(16 * nt + lo) * 64 + 32 + 8 * q4);
        }
    }

    const int rl = lane >> 3, p8 = lane & 7;
    auto stage = [&](int s0) {
        #pragma unroll
        for (int cc = 0; cc < 2; ++cc) {
            const int r = 16 * w + 8 * cc + rl;
            const int jj = p8 ^ (r & 7);
            gld_lds16(Ks + (16 * w + 8 * cc) * 64, Kp + (size_t)(s0 + r) * 64 + jj * 8);
            gld_lds16(Vs + (16 * w + 8 * cc) * 64, Vp + (size_t)r * 1024 + s0 + jj * 8);
        }
    };

    f32x4 oacc[4][2] = {};
    float lrun[2] = {0.f, 0.f};
    unsigned short* Pw = Ps + w * 2048;

    for (int i = 0; i < 16; ++i) {
        if (i) __syncthreads();       // all waves done reading Ks/Vs of chunk i-1
        stage(i * 64);
        __syncthreads();              // vmcnt drain (barrier semantics) + visibility

        // ---- S^T = K^T Q : sacc[mt][nt] ----
        f32x4 sacc[4][2] = {};
        #pragma unroll
        for (int mt = 0; mt < 4; ++mt) {
            const unsigned short* kr = Ks + (16 * mt + lo) * 64;
            const bf16x8 a0 = *(const bf16x8*)(kr + ((q4    ) ^ xr) * 8);
            const bf16x8 a1 = *(const bf16x8*)(kr + ((q4 + 4) ^ xr) * 8);
            #pragma unroll
            for (int nt = 0; nt < 2; ++nt) {
                sacc[mt][nt] = __builtin_amdgcn_mfma_f32_16x16x32_bf16(a0, qf[nt][0], sacc[mt][nt], 0, 0, 0);
                sacc[mt][nt] = __builtin_amdgcn_mfma_f32_16x16x32_bf16(a1, qf[nt][1], sacc[mt][nt], 0, 0, 0);
            }
        }

        // ---- P = exp2(S), accumulate l, truncation-pack to LDS ----
        #pragma unroll
        for (int nt = 0; nt < 2; ++nt) {
            const int t = 16 * nt + lo;
            float ps = 0.f;
            #pragma unroll
            for (int mt = 0; mt < 4; ++mt) {
                const f32x4 s = sacc[mt][nt];
                const float p0 = exp2f(s[0]);
                const float p1 = exp2f(s[1]);
                const float p2 = exp2f(s[2]);
                const float p3 = exp2f(s[3]);
                ps += (p0 + p1) + (p2 + p3);
                uint2 pk;
                pk.x = pack_trunc(p0, p1);
                pk.y = pack_trunc(p2, p3);
                const int sc = 2 * mt + (q4 >> 1);
                *(uint2*)(Pw + t * 64 + ((sc ^ xr) * 8) + 4 * (q4 & 1)) = pk;
            }
            lrun[nt] += ps;
        }

        // ---- O^T += V P^T (same-wave LDS RAW, no barrier) ----
        bf16x8 bp[2][2];
        #pragma unroll
        for (int nt = 0; nt < 2; ++nt) {
            const unsigned short* pr = Pw + (16 * nt + lo) * 64;
            bp[nt][0] = *(const bf16x8*)(pr + ((q4    ) ^ xr) * 8);
            bp[nt][1] = *(const bf16x8*)(pr + ((q4 + 4) ^ xr) * 8);
        }
        #pragma unroll
        for (int md = 0; md < 4; ++md) {
            const unsigned short* vr = Vs + (16 * md + lo) * 64;
            const bf16x8 v0 = *(const bf16x8*)(vr + ((q4    ) ^ xr) * 8);
            const bf16x8 v1 = *(const bf16x8*)(vr + ((q4 + 4) ^ xr) * 8);
            #pragma unroll
            for (int nt = 0; nt < 2; ++nt) {
                oacc[md][nt] = __builtin_amdgcn_mfma_f32_16x16x32_bf16(v0, bp[nt][0], oacc[md][nt], 0, 0, 0);
                oacc[md][nt] = __builtin_amdgcn_mfma_f32_16x16x32_bf16(v1, bp[nt][1], oacc[md][nt], 0, 0, 0);
            }
        }
    }

    // ---- epilogue: reduce l over q4 groups, write attnT[b][t][h*64+d] ----
    #pragma unroll
    for (int nt = 0; nt < 2; ++nt) {
        float lt = lrun[nt];
        lt += __shfl_xor(lt, 16, 64);
        lt += __shfl_xor(lt, 32, 64);
        const float inv = 1.0f / lt;
        const int t = tBase + 32 * w + 16 * nt + lo;
        unsigned short* op = attnT + ((size_t)(b * 1024 + t)) * 512 + h * 64;
        #pragma unroll
        for (int md = 0; md < 4; ++md) {
            uint2 pk;
            pk.x = pack_trunc(oacc[md][nt][0] * inv, oacc[md][nt][1] * inv);
            pk.y = pack_trunc(oacc[md][nt][2] * inv, oacc[md][nt][3] * inv);
            *(uint2*)(op + 16 * md + 4 * q4) = pk;
        }
    }
}

// ---------------------------------------------------------------------------
// Kernel 5: proj GEMM + bias + residual, fp32 out (unchanged).
// ---------------------------------------------------------------------------
__global__ __launch_bounds__(256)
void proj_mfma_kernel(const unsigned short* __restrict__ wpb,
                      const unsigned short* __restrict__ attnT,
                      const float* __restrict__ proj_b,
                      const float* __restrict__ x,
                      float* __restrict__ out) {
    __shared__ __align__(16) unsigned short As[128 * 32];
    __shared__ __align__(16) unsigned short Bs[128 * 32];
    const int batch = blockIdx.z;
    const int mBase = blockIdx.y * 128, nBase = blockIdx.x * 128;

    f32x4 acc[4][4] = {};
    mfma_gemm_core((const char*)(wpb + (size_t)mBase * 512),
                   (const char*)(attnT + ((size_t)batch * 1024 + nBase) * 512),
                   As, Bs, acc);

    const int tid = threadIdx.x;
    const int w = tid >> 6, lane = tid & 63;
    const int lo = lane & 15, q4 = lane >> 4;
    const int wm = w >> 1, wn = w & 1;
    const float* xb = x + (size_t)batch * 524288;
    float* ob = out + (size_t)batch * 524288;

    #pragma unroll
    for (int mi = 0; mi < 4; ++mi) {
        const int m0 = mBase + wm * 64 + mi * 16 + q4 * 4;
        const float4 bq = *(const float4*)(proj_b + m0);
        #pragma unroll
        for (int ni = 0; ni < 4; ++ni) {
            const int t = nBase + wn * 64 + ni * 16 + lo;
            const size_t o0 = (size_t)m0 * 1024 + t;
            ob[o0]          = acc[mi][ni][0] + bq.x + xb[o0];
            ob[o0 + 1024]   = acc[mi][ni][1] + bq.y + xb[o0 + 1024];
            ob[o0 + 2048]   = acc[mi][ni][2] + bq.z + xb[o0 + 2048];
            ob[o0 + 3072]   = acc[mi][ni][3] + bq.w + xb[o0 + 3072];
        }
    }
}

// ---------------------------------------------------------------------------
// Launch
// ---------------------------------------------------------------------------
extern "C" void kernel_launch(void* const* d_in, const int* in_sizes, int n_in,
                              void* d_out, int out_size, void* d_ws, size_t ws_size,
                              hipStream_t stream) {
    const float* x        = (const float*)d_in[0];
    const float* gn_gamma = (const float*)d_in[1];
    const float* gn_beta  = (const float*)d_in[2];
    const float* qkv_w    = (const float*)d_in[3];
    const float* qkv_b    = (const float*)d_in[4];
    const float* proj_w   = (const float*)d_in[5];
    const float* proj_b   = (const float*)d_in[6];
    float* out = (float*)d_out;

    // workspace layout (~86 MiB)
    char* wsc = (char*)d_ws;
    unsigned short* xnT   = (unsigned short*)(wsc);              // 16 MiB [b][t][c]
    unsigned short* Qt    = (unsigned short*)(wsc + 16777216);   // 16 MiB [bh][t][d]
    unsigned short* Kt    = (unsigned short*)(wsc + 33554432);   // 16 MiB [bh][t][d]
    unsigned short* Vb    = (unsigned short*)(wsc + 50331648);   // 16 MiB [b][d'][t]
    unsigned short* attnT = (unsigned short*)(wsc + 67108864);   // 16 MiB [b][t][c]
    unsigned short* wqb   = (unsigned short*)(wsc + 83886080);   // 1.5 MiB (wpb follows)
    unsigned short* wpb   = wqb + 786432;                        // 0.5 MiB

    // 1. GroupNorm -> xnT bf16
    groupnorm_t_kernel<<<B * NUM_GROUPS, 256, 0, stream>>>(x, gn_gamma, gn_beta, xnT);

    // 2. Weights -> bf16
    wconv_kernel<<<1024, 256, 0, stream>>>(qkv_w, proj_w, wqb);

    // 3. QKV MFMA GEMM (writes Qt, Kt, Vb directly)
    {
        dim3 grid(HW / 128, (3 * C) / 128, B);
        qkv_mfma_kernel<<<grid, 256, 0, stream>>>(wqb, xnT, qkv_b, Qt, Kt, Vb);
    }

    // 4. MFMA flash attention -> attnT bf16 (128 queries/block, 1024 blocks)
    {
        dim3 grid(B * NUM_HEADS, HW / 128);
        attn_mfma_kernel<<<grid, 256, 0, stream>>>(Qt, Kt, Vb, attnT);
    }

    // 5. Proj MFMA GEMM + bias + residual -> fp32 out
    {
        dim3 grid(HW / 128, C / 128, B);
        proj_mfma_kernel<<<grid, 256, 0, stream>>>(wpb, attnT, proj_b, x, out);
    }
}